// Round 4
// baseline (928.291 us; speedup 1.0000x reference)
//
#include <hip/hip_runtime.h>
#include <math.h>
#include <stdint.h>

typedef unsigned int u32;
typedef unsigned long long u64;

#define BLOCK 256

// ---------------------------------------------------------------------------
// Kernel 1: per-block class histograms (int4-vectorized).
// ---------------------------------------------------------------------------
template <int ITERS>
__global__ void hist_kernel(const int* __restrict__ labels, int N,
                            u32* __restrict__ hist) {
    constexpr int CHUNK = BLOCK * ITERS;
    __shared__ u32 h[4];
    int tid = threadIdx.x;
    if (tid < 4) h[tid] = 0;
    __syncthreads();
    int base4 = blockIdx.x * (CHUNK / 4);
    const int4* l4 = (const int4*)labels;
    u32 c0 = 0, c1 = 0, c2 = 0, c3 = 0;
#pragma unroll
    for (int j = 0; j < ITERS / 4; ++j) {
        int i4 = base4 + j * BLOCK + tid;
        if (4 * i4 + 3 < N) {
            int4 v = l4[i4];
            c0 += (v.x == 0) + (v.y == 0) + (v.z == 0) + (v.w == 0);
            c1 += (v.x == 1) + (v.y == 1) + (v.z == 1) + (v.w == 1);
            c2 += (v.x == 2) + (v.y == 2) + (v.z == 2) + (v.w == 2);
            c3 += (v.x == 3) + (v.y == 3) + (v.z == 3) + (v.w == 3);
        } else {
#pragma unroll
            for (int k = 0; k < 4; ++k) {
                int e = 4 * i4 + k;
                if (e < N) {
                    int l = labels[e];
                    c0 += (l == 0); c1 += (l == 1);
                    c2 += (l == 2); c3 += (l == 3);
                }
            }
        }
    }
    atomicAdd(&h[0], c0);
    atomicAdd(&h[1], c1);
    atomicAdd(&h[2], c2);
    atomicAdd(&h[3], c3);
    __syncthreads();
    if (tid < 4) hist[blockIdx.x * 4 + tid] = h[tid];
}

// ---------------------------------------------------------------------------
// Kernel 2 (single block): scan block histograms -> per-block global dst
// bases (incl. class base), class bases, init acc/done.
// ---------------------------------------------------------------------------
__global__ void scan_kernel(const u32* __restrict__ hist,
                            u32* __restrict__ boff,
                            u32* __restrict__ cbase,
                            double* __restrict__ acc,
                            u32* __restrict__ done,
                            int nb) {
    __shared__ uint4 s[BLOCK];
    __shared__ u32 sb[4];
    int t = threadIdx.x;
    int m = (nb + BLOCK - 1) / BLOCK;
    int b0 = t * m;
    int b1 = min(b0 + m, nb);
    uint4 loc = make_uint4(0, 0, 0, 0);
    for (int b = b0; b < b1; ++b) {
        loc.x += hist[b * 4 + 0];
        loc.y += hist[b * 4 + 1];
        loc.z += hist[b * 4 + 2];
        loc.w += hist[b * 4 + 3];
    }
    s[t] = loc;
    __syncthreads();
    for (int off = 1; off < BLOCK; off <<= 1) {
        uint4 v = make_uint4(0, 0, 0, 0);
        if (t >= off) v = s[t - off];
        __syncthreads();
        s[t].x += v.x; s[t].y += v.y; s[t].z += v.z; s[t].w += v.w;
        __syncthreads();
    }
    uint4 inc = s[t];
    uint4 tot = s[BLOCK - 1];
    if (t == 0) {
        sb[0] = 0;
        sb[1] = tot.x;
        sb[2] = tot.x + tot.y;
        sb[3] = tot.x + tot.y + tot.z;
        cbase[0] = sb[0]; cbase[1] = sb[1]; cbase[2] = sb[2]; cbase[3] = sb[3];
        *acc = 0.0;
        *done = 0u;
    }
    __syncthreads();
    uint4 run;
    run.x = inc.x - loc.x + sb[0];
    run.y = inc.y - loc.y + sb[1];
    run.z = inc.z - loc.z + sb[2];
    run.w = inc.w - loc.w + sb[3];
    for (int b = b0; b < b1; ++b) {
        boff[b * 4 + 0] = run.x;
        boff[b * 4 + 1] = run.y;
        boff[b * 4 + 2] = run.z;
        boff[b * 4 + 3] = run.w;
        run.x += hist[b * 4 + 0];
        run.y += hist[b * 4 + 1];
        run.z += hist[b * 4 + 2];
        run.w += hist[b * 4 + 3];
    }
}

// ---------------------------------------------------------------------------
// Kernel 3: ballot ranks -> bin rows into LDS in sorted order -> stream out
// 4 dense per-class segments (fully coalesced global writes). Also margin
// adjust, analytic sorted labels, and loss (ticket finalize).
// ---------------------------------------------------------------------------
template <int ITERS>
__global__ void __launch_bounds__(BLOCK)
main_kernel(const float4* __restrict__ data,
            const int* __restrict__ labels, int N,
            const u32* __restrict__ boff, const u32* __restrict__ cbase,
            float4* __restrict__ out_data, float* __restrict__ out_label,
            double* __restrict__ acc, u32* __restrict__ done,
            float* __restrict__ out_loss) {
    constexpr int CHUNK = BLOCK * ITERS;
    __shared__ float4 s_rows[CHUNK];
    __shared__ u32 s_cnt[ITERS][4][4];  // [j][wave][class] cnt -> excl prefix
    __shared__ u32 s_tot[4];
    __shared__ u32 s_gb[4];
    __shared__ u32 s_cb[4];
    __shared__ double s_w[4];

    const int tid = threadIdx.x;
    const int lane = tid & 63;
    const int wave = tid >> 6;
    const int base = blockIdx.x * CHUNK;
    if (tid < 8) {
        if (tid < 4) s_gb[tid] = boff[blockIdx.x * 4 + tid];
        else s_cb[tid - 4] = cbase[tid - 4];
    }

    const u64 ltm = (1ULL << lane) - 1ULL;
    float4 r[ITERS];
    u32 pre[ITERS];
    u32 pl = 0, vm = 0;
    float loss = 0.f;
    const float INV_M = 0.249999375f;  // 1/4.00001
#pragma unroll
    for (int j = 0; j < ITERS; ++j) {
        int idx = base + j * BLOCK + tid;
        bool valid = idx < N;
        int l = valid ? labels[idx] : 0;
        if (valid) r[j] = data[idx];
        u64 m0 = __ballot(valid && l == 0);
        u64 m1 = __ballot(valid && l == 1);
        u64 m2 = __ballot(valid && l == 2);
        u64 m3 = __ballot(valid && l == 3);
        if (lane == 0) {
            s_cnt[j][wave][0] = (u32)__popcll(m0);
            s_cnt[j][wave][1] = (u32)__popcll(m1);
            s_cnt[j][wave][2] = (u32)__popcll(m2);
            s_cnt[j][wave][3] = (u32)__popcll(m3);
        }
        u64 mm = (l == 0) ? m0 : (l == 1) ? m1 : (l == 2) ? m2 : m3;
        pre[j] = (u32)__popcll(mm & ltm);
        pl |= (u32)l << (2 * j);
        vm |= (valid ? 1u : 0u) << j;
        if (valid) {
            float4 rr = r[j];
            float v = (l == 0) ? rr.x : (l == 1) ? rr.y : (l == 2) ? rr.z : rr.w;
            float adj = (v > 0.f) ? (v * INV_M - 0.5f) : (v * 4.00001f - 0.5f);
            if (l == 0) rr.x = adj;
            else if (l == 1) rr.y = adj;
            else if (l == 2) rr.z = adj;
            else rr.w = adj;
            r[j] = rr;
            float mx = fmaxf(fmaxf(rr.x, rr.y), fmaxf(rr.z, rr.w));
            float se = __expf(rr.x - mx) + __expf(rr.y - mx) +
                       __expf(rr.z - mx) + __expf(rr.w - mx);
            loss += (mx + __logf(se)) - adj;
        }
    }
    __syncthreads();

    // Block scan: wave w owns class w; ITERS*4 entries in (j-major, wave) order.
    {
        constexpr int E = ITERS * 4;
        int c = wave;
        u32 x = 0, orig = 0;
        if (lane < E) { orig = s_cnt[lane >> 2][lane & 3][c]; x = orig; }
#pragma unroll
        for (int off = 1; off < E; off <<= 1) {
            u32 v = (u32)__shfl_up((int)x, off, 64);
            if (lane >= off && lane < E) x += v;
        }
        if (lane < E) s_cnt[lane >> 2][lane & 3][c] = x - orig;
        if (lane == E - 1) s_tot[c] = x;
    }
    __syncthreads();

    const u32 t0 = s_tot[0], t1 = s_tot[1], t2 = s_tot[2], t3 = s_tot[3];
    const u32 lcb1 = t0, lcb2 = t0 + t1, lcb3 = t0 + t1 + t2;
    const u32 totrows = lcb3 + t3;

    // Bin rows into LDS at locally-sorted positions.
#pragma unroll
    for (int j = 0; j < ITERS; ++j) {
        if ((vm >> j) & 1) {
            int l = (pl >> (2 * j)) & 3;
            u32 lcb = (l == 0) ? 0u : (l == 1) ? lcb1 : (l == 2) ? lcb2 : lcb3;
            u32 ldst = lcb + s_cnt[j][wave][l] + pre[j];
            s_rows[ldst] = r[j];
        }
    }
    __syncthreads();

    // Stream out: consecutive lanes -> consecutive global rows per class seg.
    {
        u32 g0 = s_gb[0], g1 = s_gb[1], g2 = s_gb[2], g3 = s_gb[3];
        // gdst = i + (gb[c] - lcb[c])
        u32 d0 = g0, d1 = g1 - lcb1, d2 = g2 - lcb2, d3 = g3 - lcb3;
#pragma unroll
        for (int j = 0; j < ITERS; ++j) {
            u32 i = j * BLOCK + tid;
            if (i < totrows) {
                u32 add = (i < lcb1) ? d0 : (i < lcb2) ? d1
                        : (i < lcb3) ? d2 : d3;
                out_data[i + add] = s_rows[i];
            }
        }
    }

    // Analytic sorted labels for this block's own index range.
    {
        u32 b1 = s_cb[1], b2 = s_cb[2], b3 = s_cb[3];
#pragma unroll
        for (int j = 0; j < ITERS / 4; ++j) {
            int i4 = (base >> 2) + j * BLOCK + tid;
            int j0 = i4 * 4;
            if (j0 + 3 < N) {
                float4 rr;
                u32 ju = (u32)j0;
                rr.x = (float)((ju >= b1) + (ju >= b2) + (ju >= b3));
                rr.y = (float)((ju + 1 >= b1) + (ju + 1 >= b2) + (ju + 1 >= b3));
                rr.z = (float)((ju + 2 >= b1) + (ju + 2 >= b2) + (ju + 2 >= b3));
                rr.w = (float)((ju + 3 >= b1) + (ju + 3 >= b2) + (ju + 3 >= b3));
                ((float4*)out_label)[i4] = rr;
            } else {
                for (int k = 0; k < 4; ++k) {
                    int jj = j0 + k;
                    if (jj < N) {
                        u32 ju = (u32)jj;
                        out_label[jj] =
                            (float)((ju >= b1) + (ju >= b2) + (ju >= b3));
                    }
                }
            }
        }
    }

    // Loss: block reduce (double) + one atomic + ticket finalize.
    double d = (double)loss;
#pragma unroll
    for (int off = 32; off > 0; off >>= 1) d += __shfl_down(d, off, 64);
    if (lane == 0) s_w[wave] = d;
    __syncthreads();
    if (tid == 0) {
        atomicAdd(acc, s_w[0] + s_w[1] + s_w[2] + s_w[3]);
        __threadfence();
        u32 t = atomicAdd(done, 1u);
        if (t == (u32)(gridDim.x - 1)) {
            __threadfence();
            double totloss = atomicAdd(acc, 0.0);
            *out_loss = (float)(totloss / (double)N);
        }
    }
}

// ---------------------------------------------------------------------------
template <int ITERS>
static void launch_all(const float* data, const int* labels, int N,
                       void* d_out, void* d_ws, hipStream_t stream) {
    constexpr int CHUNK = BLOCK * ITERS;
    int nb = (N + CHUNK - 1) / CHUNK;

    u32* hist = (u32*)d_ws;
    u32* boff = hist + (size_t)nb * 4;
    u32* cbase = boff + (size_t)nb * 4;
    double* acc = (double*)(((uintptr_t)(cbase + 4) + 15) & ~(uintptr_t)15);
    u32* done = (u32*)(acc + 1);

    float* out = (float*)d_out;
    float* out_data = out;                   // N*4
    float* out_label = out + (size_t)N * 4;  // N
    float* out_loss = out + (size_t)N * 5;   // 1

    hist_kernel<ITERS><<<nb, BLOCK, 0, stream>>>(labels, N, hist);
    scan_kernel<<<1, BLOCK, 0, stream>>>(hist, boff, cbase, acc, done, nb);
    main_kernel<ITERS><<<nb, BLOCK, 0, stream>>>(
        (const float4*)data, labels, N, boff, cbase, (float4*)out_data,
        out_label, acc, done, out_loss);
}

extern "C" void kernel_launch(void* const* d_in, const int* in_sizes, int n_in,
                              void* d_out, int out_size, void* d_ws,
                              size_t ws_size, hipStream_t stream) {
    const float* data = (const float*)d_in[0];
    const int* labels = (const int*)d_in[1];
    int N = in_sizes[1];

    // ws requirement: nb*8 u32 + ~64 B. Prefer CHUNK=1024 (full occupancy).
    size_t nb4 = ((size_t)N + 1023) / 1024;
    if (ws_size >= nb4 * 8 * sizeof(u32) + 64) {
        launch_all<4>(data, labels, N, d_out, d_ws, stream);
    } else {
        launch_all<8>(data, labels, N, d_out, d_ws, stream);
    }
}